// Round 8
// baseline (152.362 us; speedup 1.0000x reference)
//
#include <hip/hip_runtime.h>
#include <hip/hip_bf16.h>

#define T_SEQ   2048
#define BATCH   2
#define DMODEL  1024
#define NHEADS  16
#define HDIM    64
#define WINDOW  128

typedef __attribute__((ext_vector_type(8))) short bf16x8;
typedef __attribute__((ext_vector_type(4))) float f32x4;

// async global->LDS 16B per lane (attn K staging only)
__device__ inline void gld_lds16(const __hip_bfloat16* g, __hip_bfloat16* l) {
    __builtin_amdgcn_global_load_lds(
        (const __attribute__((address_space(1))) unsigned int*)g,
        (__attribute__((address_space(3))) unsigned int*)l, 16, 0, 0);
}

// ---------------------------------------------------------------------------
// Fragment layout (R8): matrices consumed by the no-LDS GEMMs are stored so
// one wave fragment-load is a single coalesced 1KB global_load_dwordx4.
//   FIDX(row,k) = (((row>>4)*32 + (k>>5))*64 + (k>>3 & 3)*16 + (row&15))*8 + (k&7)
// Wave load for (tile16 mt, k32 ss): base + ((mt*32+ss)*64 + lane)*8 — the
// lane permutation quad*16+lrow == lane, so the load is contiguous. Verified
// by construction in cvt (writer) and both GEMMs (readers).
// ---------------------------------------------------------------------------

// fp32 -> bf16 convert INTO fragment order. Same grid as before:
// lid<2048 -> x (4096x1024 -> A'), else 512 blocks per weight slot (1024x1024).
// Thread u owns dst unit u (8 elems, contiguous writes); source read is
// 32B/thread, full-line utilized per wave (quad-groups cover 128B per row).
__global__ __launch_bounds__(256) void cvt_kernel(
    const float* __restrict__ x,  const float* __restrict__ Wq,
    const float* __restrict__ Wk, const float* __restrict__ Wv,
    const float* __restrict__ Wo,
    __hip_bfloat16* __restrict__ xb, __hip_bfloat16* __restrict__ Wb)
{
    const int lid = blockIdx.x;
    const float* src;
    __hip_bfloat16* dst;
    int ublk;
    if (lid < 2048) { src = x; dst = xb; ublk = lid; }
    else {
        int slot = (lid - 2048) >> 9;           // 0..3
        ublk = (lid - 2048) & 511;
        src = (slot == 0) ? Wq : (slot == 1) ? Wk : (slot == 2) ? Wv : Wo;
        dst = Wb + (size_t)slot * 1024 * 1024;
    }
    const int u    = ublk * 256 + threadIdx.x;   // fragment unit index
    const int lrow = u & 15;
    const int quad = (u >> 4) & 3;
    const int g    = u >> 6;
    const int k32  = g & 31;
    const int t16  = g >> 5;
    const int row  = t16 * 16 + lrow;
    const int k    = k32 * 32 + quad * 8;

    const float* sp = src + (size_t)row * 1024 + k;
    float4 a = *(const float4*)sp;
    float4 b = *(const float4*)(sp + 4);
    __hip_bfloat16 pk[8] = {
        __float2bfloat16(a.x), __float2bfloat16(a.y),
        __float2bfloat16(a.z), __float2bfloat16(a.w),
        __float2bfloat16(b.x), __float2bfloat16(b.y),
        __float2bfloat16(b.z), __float2bfloat16(b.w)};
    *(uint4*)(dst + (size_t)u * 8) = *(uint4*)pk;
}

// ---------------------------------------------------------------------------
// QKV GEMM v8: NO LDS, NO BARRIERS. 128x128 block, 4 waves (64x64/wave),
// grid 768 = 3 blocks/CU (12 waves), free-running.
// Each k32-step: 8 coalesced fragment loads (VGPR) + 16 MFMAs, 2-deep
// register double-buffer (named bufs, static indexing — rule 20).
// The R1-R7 invariant 21% MfmaUtil was the LDS port (~2300 cyc traffic vs
// 1242 cyc MFMA per CU per tile-pair); this removes LDS from the path.
// XCD map: xcd owns 8bm x 12bn -> A 2MB + B 3MB working set per XCD L2.
// ---------------------------------------------------------------------------
__global__ __launch_bounds__(256, 3) void gemm_qkv(
    const __hip_bfloat16* __restrict__ Af,   // x in fragment order [4096,1024]
    const __hip_bfloat16* __restrict__ Bf,   // packed [Wq;Wk;Wv] frag order [3072,1024]
    __hip_bfloat16* __restrict__ C0,
    __hip_bfloat16* __restrict__ C1,
    __hip_bfloat16* __restrict__ C2)
{
    const int lid = blockIdx.x;
    const int xcd = lid & 7;
    const int s   = lid >> 3;                 // 0..95
    const int bm  = (xcd & 3) * 8 + s / 12;   // 0..31
    const int bn  = (xcd >> 2) * 12 + s % 12; // 0..23
    const int m0 = bm * 128, n0 = bn * 128;
    const int z = n0 >> 10, cbase = n0 & 1023;

    const int t    = threadIdx.x;
    const int lane = t & 63;
    const int wv   = t >> 6;
    const int lrow = lane & 15;
    const int quad = lane >> 4;
    const int wm   = (wv >> 1) * 64;
    const int wn   = (wv & 1) * 64;

    // wave fragment bases: + (i*32 + ss)*512 elems selects (tile i, k32 ss)
    const __hip_bfloat16* Ab = Af + (((size_t)((m0 + wm) >> 4) * 32) * 64 + lane) * 8;
    const __hip_bfloat16* Bb = Bf + (((size_t)((n0 + wn) >> 4) * 32) * 64 + lane) * 8;

    f32x4 acc[4][4];
#pragma unroll
    for (int i = 0; i < 4; ++i)
#pragma unroll
        for (int j = 0; j < 4; ++j)
            acc[i][j] = (f32x4){0.f, 0.f, 0.f, 0.f};

    bf16x8 a0[4], b0[4], a1[4], b1[4];

    auto LDA = [&](bf16x8* d, int ss) {
#pragma unroll
        for (int i = 0; i < 4; ++i)
            d[i] = *(const bf16x8*)(Ab + ((size_t)(i * 32 + ss)) * 512);
    };
    auto LDB = [&](bf16x8* d, int ss) {
#pragma unroll
        for (int i = 0; i < 4; ++i)
            d[i] = *(const bf16x8*)(Bb + ((size_t)(i * 32 + ss)) * 512);
    };

    LDA(a0, 0); LDB(b0, 0);

    for (int ss = 0; ss < 32; ss += 2) {
        LDA(a1, ss + 1); LDB(b1, ss + 1);
#pragma unroll
        for (int mi = 0; mi < 4; ++mi)
#pragma unroll
            for (int ni = 0; ni < 4; ++ni)
                acc[mi][ni] = __builtin_amdgcn_mfma_f32_16x16x32_bf16(
                    a0[mi], b0[ni], acc[mi][ni], 0, 0, 0);
        const int s2 = (ss + 2 < 32) ? ss + 2 : 31;   // dummy refetch on last
        LDA(a0, s2); LDB(b0, s2);
#pragma unroll
        for (int mi = 0; mi < 4; ++mi)
#pragma unroll
            for (int ni = 0; ni < 4; ++ni)
                acc[mi][ni] = __builtin_amdgcn_mfma_f32_16x16x32_bf16(
                    a1[mi], b1[ni], acc[mi][ni], 0, 0, 0);
    }

    // per-head l2norm for Q,K (wave cols = exactly one 64-wide head)
    if (z != 2) {
#pragma unroll
        for (int mi = 0; mi < 4; ++mi) {
#pragma unroll
            for (int rr = 0; rr < 4; ++rr) {
                float ss2 = 0.f;
#pragma unroll
                for (int ni = 0; ni < 4; ++ni)
                    ss2 += acc[mi][ni][rr] * acc[mi][ni][rr];
                ss2 += __shfl_xor(ss2, 1);
                ss2 += __shfl_xor(ss2, 2);
                ss2 += __shfl_xor(ss2, 4);
                ss2 += __shfl_xor(ss2, 8);
                float inv = 1.0f / fmaxf(sqrtf(ss2), 1e-6f);
#pragma unroll
                for (int ni = 0; ni < 4; ++ni)
                    acc[mi][ni][rr] *= inv;
            }
        }
    }

    __hip_bfloat16* C = (z == 0) ? C0 : (z == 1) ? C1 : C2;
    // C/D layout col=lane&15, row=quad*4+reg  [verified m89/m91]; Q/K/V kept
    // in standard [4096][1024] layout (attn input unchanged).
#pragma unroll
    for (int mi = 0; mi < 4; ++mi) {
#pragma unroll
        for (int rr = 0; rr < 4; ++rr) {
            int row = m0 + wm + mi * 16 + quad * 4 + rr;
            __hip_bfloat16* Crow = C + (size_t)row * DMODEL + cbase + wn + lrow;
#pragma unroll
            for (int ni = 0; ni < 4; ++ni)
                Crow[ni * 16] = __float2bfloat16(acc[mi][ni][rr]);
        }
    }
}

// ---------------------------------------------------------------------------
// O-projection GEMM v8: same no-LDS structure. 64x128 block, 4 waves
// (32x64/wave), grid 512 = 2 blocks/CU. A = attn output in fragment order,
// B = Wo in fragment order, C = fp32 standard. XCD map: xcd owns 8bm x 8bn
// (A 1MB + B 2MB resident).
// ---------------------------------------------------------------------------
__global__ __launch_bounds__(256, 2) void gemm_o(
    const __hip_bfloat16* __restrict__ Af,   // AO fragment order [4096,1024]
    const __hip_bfloat16* __restrict__ Bf,   // Wo fragment order [1024,1024]
    float* __restrict__ C)
{
    const int lid  = blockIdx.x;
    const int wgid = (lid & 7) * 64 + (lid >> 3);   // 512 % 8 == 0: bijective
    const int bm   = wgid >> 3;    // 0..63 (64-row tiles)
    const int bn   = wgid & 7;     // 0..7  (128-col tiles)
    const int m0   = bm * 64;
    const int n0   = bn * 128;

    const int t    = threadIdx.x;
    const int lane = t & 63;
    const int wv   = t >> 6;
    const int lrow = lane & 15;
    const int quad = lane >> 4;
    const int wm   = (wv >> 1) * 32;
    const int wn   = (wv & 1) * 64;

    const __hip_bfloat16* Ab = Af + (((size_t)((m0 + wm) >> 4) * 32) * 64 + lane) * 8;
    const __hip_bfloat16* Bb = Bf + (((size_t)((n0 + wn) >> 4) * 32) * 64 + lane) * 8;

    f32x4 acc[2][4];
#pragma unroll
    for (int i = 0; i < 2; ++i)
#pragma unroll
        for (int j = 0; j < 4; ++j)
            acc[i][j] = (f32x4){0.f, 0.f, 0.f, 0.f};

    bf16x8 a0[2], b0[4], a1[2], b1[4];

    auto LDA = [&](bf16x8* d, int ss) {
#pragma unroll
        for (int i = 0; i < 2; ++i)
            d[i] = *(const bf16x8*)(Ab + ((size_t)(i * 32 + ss)) * 512);
    };
    auto LDB = [&](bf16x8* d, int ss) {
#pragma unroll
        for (int i = 0; i < 4; ++i)
            d[i] = *(const bf16x8*)(Bb + ((size_t)(i * 32 + ss)) * 512);
    };

    LDA(a0, 0); LDB(b0, 0);

    for (int ss = 0; ss < 32; ss += 2) {
        LDA(a1, ss + 1); LDB(b1, ss + 1);
#pragma unroll
        for (int mi = 0; mi < 2; ++mi)
#pragma unroll
            for (int ni = 0; ni < 4; ++ni)
                acc[mi][ni] = __builtin_amdgcn_mfma_f32_16x16x32_bf16(
                    a0[mi], b0[ni], acc[mi][ni], 0, 0, 0);
        const int s2 = (ss + 2 < 32) ? ss + 2 : 31;
        LDA(a0, s2); LDB(b0, s2);
#pragma unroll
        for (int mi = 0; mi < 2; ++mi)
#pragma unroll
            for (int ni = 0; ni < 4; ++ni)
                acc[mi][ni] = __builtin_amdgcn_mfma_f32_16x16x32_bf16(
                    a1[mi], b1[ni], acc[mi][ni], 0, 0, 0);
    }

#pragma unroll
    for (int mi = 0; mi < 2; ++mi) {
#pragma unroll
        for (int rr = 0; rr < 4; ++rr) {
            int row = m0 + wm + mi * 16 + quad * 4 + rr;
            float* Crow = C + (size_t)row * DMODEL + n0 + wn + lrow;
#pragma unroll
            for (int ni = 0; ni < 4; ++ni)
                Crow[ni * 16] = acc[mi][ni][rr];
        }
    }
}

// MFMA sliding-window attention, 128-query blocks (8 waves, 512 thr).
// R8: final __syncthreads removed (PV reads only own-wave P region — the
// same-wave LDS RAW is compiler-ordered via lgkmcnt); O written in A'
// fragment order for the no-LDS gemm_o.
__global__ __launch_bounds__(512) void attn_kernel(
    const __hip_bfloat16* __restrict__ Q,
    const __hip_bfloat16* __restrict__ K,
    const __hip_bfloat16* __restrict__ V,
    __hip_bfloat16* __restrict__ O)       // fragment-order output
{
    const int qb = blockIdx.x * 128;
    const int h  = blockIdx.y;
    const int b  = blockIdx.z;

    __shared__ __hip_bfloat16 KsP[8 * 16 * 168];  // >= 256*64; P overlay later
    __shared__ __hip_bfloat16 Vt[64 * 264];       // V^T, swizzled key blocks

    const size_t base = ((size_t)b * T_SEQ) * DMODEL + h * HDIM;
    const int t    = threadIdx.x;
    const int lane = t & 63;
    const int w    = t >> 6;                      // wave 0..7
    const int col  = lane & 15;
    const int quad = lane >> 4;

    // K staging via DMA: wave w covers rows [w*32, w*32+32), 4 insts of 8 rows.
    {
        const int drow = lane >> 3, sl = lane & 7;
#pragma unroll
        for (int inst = 0; inst < 4; inst++) {
            int r0 = w * 32 + inst * 8;
            int r  = r0 + drow;
            int gcx = (sl - r) & 7;
            int j  = min(qb + r, T_SEQ - 1);
            gld_lds16(K + base + (size_t)j * DMODEL + gcx * 8, &KsP[r0 * 64]);
        }
    }

    // Q fragment loads: independent of staging — issue before the barrier.
    const __hip_bfloat16* qp = Q + base + (size_t)(qb + w * 16 + col) * DMODEL + quad * 8;
    bf16x8 qf0 = *(const bf16x8*)(qp);
    bf16x8 qf1 = *(const bf16x8*)(qp + 32);

    // V staging: 512 tasks (dim-chunk c, key-block b0, half hf), 8x4 register
    // transpose each, swizzled writes: sg = (b0&~7)|((b0+c)&7).
    {
        int c  = t & 7;
        int b0 = (t >> 3) & 31;
        int hf = t >> 8;              // 0..1
        int sg = (b0 & ~7) | ((b0 + c) & 7);
        unsigned short m[8][4];
#pragma unroll
        for (int i = 0; i < 4; i++) {
            int j = min(qb + b0 * 8 + hf * 4 + i, T_SEQ - 1);
            uint4 u = *(const uint4*)(V + base + (size_t)j * DMODEL + c * 8);
            unsigned short tmp[8];
            *(uint4*)tmp = u;
#pragma unroll
            for (int e = 0; e < 8; e++) m[e][i] = tmp[e];
        }
#pragma unroll
        for (int e = 0; e < 8; e++)
            *(uint2*)&Vt[(c * 8 + e) * 264 + sg * 8 + hf * 4] = *(uint2*)m[e];
    }
    // zero tail slot 32 (keys >= 256; P is zero there but data must be finite)
    if (t < 64) {
        uint4 zz = {0, 0, 0, 0};
        *(uint4*)&Vt[t * 264 + 256] = zz;
    }
    __syncthreads();

    const float slope = exp2f(-8.0f * (float)h / 15.0f);

    f32x4 sc[9];
#pragma unroll
    for (int kt = 0; kt < 9; kt++) {
        sc[kt] = (f32x4){0.f, 0.f, 0.f, 0.f};
        int r = w * 16 + kt * 16 + col;
        bf16x8 kb0 = *(const bf16x8*)&KsP[r * 64 + ((quad     + r) & 7) * 8];
        bf16x8 kb1 = *(const bf16x8*)&KsP[r * 64 + ((quad + 4 + r) & 7) * 8];
        sc[kt] = __builtin_amdgcn_mfma_f32_16x16x32_bf16(qf0, kb0, sc[kt], 0, 0, 0);
        sc[kt] = __builtin_amdgcn_mfma_f32_16x16x32_bf16(qf1, kb1, sc[kt], 0, 0, 0);
    }

    float mx[4] = {-3e38f, -3e38f, -3e38f, -3e38f};
#pragma unroll
    for (int kt = 0; kt < 9; kt++) {
#pragma unroll
        for (int r = 0; r < 4; r++) {
            int ql  = quad * 4 + r;
            int rel = kt * 16 + col - ql;
            int ka  = qb + w * 16 + kt * 16 + col;
            bool valid = (rel >= 0) && (rel < WINDOW) && (ka < T_SEQ);
            float v = valid ? (sc[kt][r] - (float)rel * slope) : -1e30f;
            sc[kt][r] = v;
            mx[r] = fmaxf(mx[r], v);
        }
    }
#pragma unroll
    for (int r = 0; r < 4; r++) {
        mx[r] = fmaxf(mx[r], __shfl_xor(mx[r], 1));
        mx[r] = fmaxf(mx[r], __shfl_xor(mx[r], 2));
        mx[r] = fmaxf(mx[r], __shfl_xor(mx[r], 4));
        mx[r] = fmaxf(mx[r], __shfl_xor(mx[r], 8));
    }
    float sm[4] = {0.f, 0.f, 0.f, 0.f};
#pragma unroll
    for (int kt = 0; kt < 9; kt++) {
#pragma unroll
        for (int r = 0; r < 4; r++) {
            float e = __expf(sc[kt][r] - mx[r]);
            sc[kt][r] = e;
            sm[r] += e;
        }
    }
#pragma unroll
    for (int r = 0; r < 4; r++) {
        sm[r] += __shfl_xor(sm[r], 1);
        sm[r] += __shfl_xor(sm[r], 2);
        sm[r] += __shfl_xor(sm[r], 4);
        sm[r] += __shfl_xor(sm[r], 8);
        sm[r] = 1.0f / sm[r];
    }

    // all Ks reads done -> overlay P (per-wave region, stride 168).
    // This barrier IS required: wave w's P region overlaps Ks rows read by
    // neighboring waves.
    __syncthreads();
    __hip_bfloat16* Ps = KsP + w * (16 * 168);
#pragma unroll
    for (int kt = 0; kt < 9; kt++)
#pragma unroll
        for (int r = 0; r < 4; r++)
            Ps[(quad * 4 + r) * 168 + kt * 16 + col] = __float2bfloat16(sc[kt][r] * sm[r]);
#pragma unroll
    for (int i = 0; i < 4; i++)
        Ps[(lane & 15) * 168 + 144 + quad * 4 + i] = __float2bfloat16(0.f);
    // no barrier: PV reads only this wave's P region (same-wave LDS ordering)

    // PV: A = P[q][key], B = Vt[dim][key] (swizzled slots)
    f32x4 o[4];
#pragma unroll
    for (int nd = 0; nd < 4; nd++) o[nd] = (f32x4){0.f, 0.f, 0.f, 0.f};
#pragma unroll
    for (int kc = 0; kc < 5; kc++) {
        bf16x8 pf = *(const bf16x8*)&Ps[col * 168 + kc * 32 + quad * 8];
        int bblk = w * 2 + kc * 4 + quad;
#pragma unroll
        for (int nd = 0; nd < 4; nd++) {
            int d  = nd * 16 + col;
            int sg = (bblk < 32) ? ((bblk & ~7) | ((bblk + (d >> 3)) & 7)) : 32;
            bf16x8 vf = *(const bf16x8*)&Vt[d * 264 + sg * 8];
            o[nd] = __builtin_amdgcn_mfma_f32_16x16x32_bf16(pf, vf, o[nd], 0, 0, 0);
        }
    }

    // O-write in A' fragment order: FIDX(row_g, k_g)
#pragma unroll
    for (int r = 0; r < 4; r++) {
        int row_g = b * T_SEQ + qb + w * 16 + quad * 4 + r;
        int rt = row_g >> 4, rl = row_g & 15;
#pragma unroll
        for (int nd = 0; nd < 4; nd++) {
            int k_g = h * HDIM + nd * 16 + col;
            size_t idx = (((size_t)rt * 32 + (k_g >> 5)) * 64
                          + ((k_g >> 3) & 3) * 16 + rl) * 8 + (k_g & 7);
            O[idx] = __float2bfloat16(o[nd][r]);
        }
    }
}

extern "C" void kernel_launch(void* const* d_in, const int* in_sizes, int n_in,
                              void* d_out, int out_size, void* d_ws, size_t ws_size,
                              hipStream_t stream)
{
    const float* x  = (const float*)d_in[0];
    const float* Wq = (const float*)d_in[1];
    const float* Wk = (const float*)d_in[2];
    const float* Wv = (const float*)d_in[3];
    const float* Wo = (const float*)d_in[4];
    float* out = (float*)d_out;

    const size_t MT = (size_t)BATCH * T_SEQ;          // 4096 rows
    __hip_bfloat16* Qw = (__hip_bfloat16*)d_ws;       // 8 MB each (bf16)
    __hip_bfloat16* Kw = Qw + MT * DMODEL;
    __hip_bfloat16* Vw = Kw + MT * DMODEL;
    __hip_bfloat16* XA = Vw + MT * DMODEL;            // A' (pre-attn) / AO' (post-attn)
    __hip_bfloat16* Wb = XA + MT * DMODEL;            // 4 x 1M bf16 weights (frag order)

    cvt_kernel<<<4096, 256, 0, stream>>>(x, Wq, Wk, Wv, Wo, XA, Wb);

    // fused QKV: packed frag-order weights [Wq;Wk;Wv] = 3072x1024
    gemm_qkv<<<dim3(768), 256, 0, stream>>>(XA, Wb, Qw, Kw, Vw);

    dim3 g2(T_SEQ / 128, NHEADS, BATCH);
    attn_kernel<<<g2, 512, 0, stream>>>(Qw, Kw, Vw, XA);

    gemm_o<<<dim3(512), 256, 0, stream>>>(XA, Wb + 3 * 1024 * 1024, out);
}